// Round 1
// baseline (2452.180 us; speedup 1.0000x reference)
//
#include <hip/hip_runtime.h>
#include <cmath>

#define EPSV 1e-5f
#define NEG_SLOPE 0.2f
#define FDIM 256

// ---------------- CSR build ----------------
__global__ __launch_bounds__(256) void count_kernel(const int* __restrict__ dstv,
                                                    int* __restrict__ counts, int E) {
  int e = blockIdx.x * 256 + threadIdx.x;
  if (e < E) atomicAdd(&counts[dstv[e]], 1);
}

__global__ __launch_bounds__(1024) void scan_kernel(const int* __restrict__ counts,
                                                    int* __restrict__ row_start, int Nn) {
  __shared__ int lds[1024];
  int t = threadIdx.x;
  int C = (Nn + 1023) >> 10;
  int beg = t * C;
  int end = min(beg + C, Nn);
  int s = 0;
  for (int i = beg; i < end; ++i) s += counts[i];
  lds[t] = s;
  __syncthreads();
  for (int off = 1; off < 1024; off <<= 1) {
    int v = (t >= off) ? lds[t - off] : 0;
    __syncthreads();
    lds[t] += v;
    __syncthreads();
  }
  int run = (t > 0) ? lds[t - 1] : 0;
  for (int i = beg; i < end; ++i) { row_start[i] = run; run += counts[i]; }
  if (t == 1023) row_start[Nn] = lds[1023];
}

__global__ __launch_bounds__(256) void fill_kernel(const int* __restrict__ srcv,
                                                   const int* __restrict__ dstv,
                                                   const int* __restrict__ row_start,
                                                   int* __restrict__ cursor,
                                                   int* __restrict__ col_src, int E) {
  int e = blockIdx.x * 256 + threadIdx.x;
  if (e < E) {
    int d = dstv[e];
    int pos = atomicAdd(&cursor[d], 1);
    col_src[row_start[d] + pos] = srcv[e];
  }
}

// ---------------- fp32 tiled GEMM: C = A(MxK) * B(KxN) [+ bias] ----------------
// BM=BN=128, BK=8, 256 threads, 8x8 per thread. N must be a multiple of 128 (always 256 here).
__global__ __launch_bounds__(256) void gemm_f32_kernel(
    const float* __restrict__ A, const float* __restrict__ B,
    const float* __restrict__ bias, float* __restrict__ C,
    int M, int N, int K) {
  const int BM = 128, BN = 128, BK = 8;
  __shared__ float As[BK][BM];
  __shared__ float Bs[BK][BN];
  int tid = threadIdx.x;
  int row0 = blockIdx.x * BM;
  int col0 = blockIdx.y * BN;
  int a_row = tid >> 1;          // 0..127
  int a_k = (tid & 1) << 2;      // 0 or 4
  int b_k = tid >> 5;            // 0..7
  int b_col = (tid & 31) << 2;   // 0..124
  int tr = (tid >> 4) << 3;      // 0..120
  int tc = (tid & 15) << 3;      // 0..120
  float acc[8][8];
#pragma unroll
  for (int i = 0; i < 8; ++i)
#pragma unroll
    for (int j = 0; j < 8; ++j) acc[i][j] = 0.f;

  int ar = row0 + a_row;
  const float* Arow = A + (size_t)ar * K;
  int ktiles = (K + BK - 1) / BK;
  for (int kt = 0; kt < ktiles; ++kt) {
    int kbase = kt * BK;
    // stage A (scalar loads: K may be odd, rows not 16B-aligned)
    float a0 = 0.f, a1 = 0.f, a2 = 0.f, a3 = 0.f;
    if (ar < M) {
      int kg = kbase + a_k;
      if (kg + 3 < K) {
        a0 = Arow[kg]; a1 = Arow[kg + 1]; a2 = Arow[kg + 2]; a3 = Arow[kg + 3];
      } else {
        if (kg < K)     a0 = Arow[kg];
        if (kg + 1 < K) a1 = Arow[kg + 1];
        if (kg + 2 < K) a2 = Arow[kg + 2];
      }
    }
    As[a_k + 0][a_row] = a0;
    As[a_k + 1][a_row] = a1;
    As[a_k + 2][a_row] = a2;
    As[a_k + 3][a_row] = a3;
    // stage B (rows are 16B aligned: N=256)
    float4 bv = make_float4(0.f, 0.f, 0.f, 0.f);
    int kg = kbase + b_k;
    if (kg < K) bv = *reinterpret_cast<const float4*>(B + (size_t)kg * N + (col0 + b_col));
    *reinterpret_cast<float4*>(&Bs[b_k][b_col]) = bv;
    __syncthreads();
#pragma unroll
    for (int kk = 0; kk < BK; ++kk) {
      float4 av0 = *reinterpret_cast<const float4*>(&As[kk][tr]);
      float4 av1 = *reinterpret_cast<const float4*>(&As[kk][tr + 4]);
      float4 bv0 = *reinterpret_cast<const float4*>(&Bs[kk][tc]);
      float4 bv1 = *reinterpret_cast<const float4*>(&Bs[kk][tc + 4]);
      float a[8] = {av0.x, av0.y, av0.z, av0.w, av1.x, av1.y, av1.z, av1.w};
      float b[8] = {bv0.x, bv0.y, bv0.z, bv0.w, bv1.x, bv1.y, bv1.z, bv1.w};
#pragma unroll
      for (int i = 0; i < 8; ++i)
#pragma unroll
        for (int j = 0; j < 8; ++j)
          acc[i][j] = fmaf(a[i], b[j], acc[i][j]);
    }
    __syncthreads();
  }
#pragma unroll
  for (int i = 0; i < 8; ++i) {
    int r = row0 + tr + i;
    if (r < M) {
      float* Crow = C + (size_t)r * N + col0;
#pragma unroll
      for (int j = 0; j < 8; j += 4) {
        int c = tc + j;
        float4 v = make_float4(acc[i][j], acc[i][j + 1], acc[i][j + 2], acc[i][j + 3]);
        if (bias) {
          const float4 bb = *reinterpret_cast<const float4*>(bias + col0 + c);
          v.x += bb.x; v.y += bb.y; v.z += bb.z; v.w += bb.w;
        }
        *reinterpret_cast<float4*>(Crow + c) = v;
      }
    }
  }
}

// ---------------- attention scores: s_src[i]=h[i]·a_src, s_dst[i]=h[i]·a_dst ----------------
__global__ __launch_bounds__(64) void scores_kernel(
    const float* __restrict__ h, const float* __restrict__ a_src,
    const float* __restrict__ a_dst, float* __restrict__ s_src,
    float* __restrict__ s_dst) {
  int node = blockIdx.x;
  int lane = threadIdx.x;  // 64 lanes * 4 floats = 256 features
  const float4 hv = *reinterpret_cast<const float4*>(h + (size_t)node * FDIM + lane * 4);
  const float4 as = *reinterpret_cast<const float4*>(a_src + lane * 4);
  const float4 ad = *reinterpret_cast<const float4*>(a_dst + lane * 4);
  float vs = hv.x * as.x + hv.y * as.y + hv.z * as.z + hv.w * as.w;
  float vd = hv.x * ad.x + hv.y * ad.y + hv.z * ad.z + hv.w * ad.w;
#pragma unroll
  for (int off = 32; off > 0; off >>= 1) {
    vs += __shfl_down(vs, off);
    vd += __shfl_down(vd, off);
  }
  if (lane == 0) { s_src[node] = vs; s_dst[node] = vd; }
}

// ---------------- GAT aggregate: online softmax over in-edges + self-loop, +bias, ELU ----------------
__global__ __launch_bounds__(64) void gat_aggregate_kernel(
    const float* __restrict__ h, const float* __restrict__ s_src,
    const float* __restrict__ s_dst, const float* __restrict__ bias,
    const int* __restrict__ row_start, const int* __restrict__ col_src,
    float* __restrict__ out) {
  int i = blockIdx.x;
  int lane = threadIdx.x;
  int f = lane * 4;
  float sd = s_dst[i];
  // self-loop initializes the running softmax (guarantees non-empty segment)
  float e0 = s_src[i] + sd;
  e0 = e0 > 0.f ? e0 : NEG_SLOPE * e0;
  float m = e0, l = 1.f;
  float4 acc = *reinterpret_cast<const float4*>(h + (size_t)i * FDIM + f);
  int beg = row_start[i], end = row_start[i + 1];
  for (int p = beg; p < end; ++p) {
    int j = col_src[p];                       // wave-uniform
    float e = s_src[j] + sd;
    e = e > 0.f ? e : NEG_SLOPE * e;
    float mn = fmaxf(m, e);
    float sc = __expf(m - mn);
    float pw = __expf(e - mn);
    l = l * sc + pw;
    const float4 hj = *reinterpret_cast<const float4*>(h + (size_t)j * FDIM + f);
    acc.x = acc.x * sc + pw * hj.x;
    acc.y = acc.y * sc + pw * hj.y;
    acc.z = acc.z * sc + pw * hj.z;
    acc.w = acc.w * sc + pw * hj.w;
    m = mn;
  }
  float inv = 1.f / l;
  const float4 bv = *reinterpret_cast<const float4*>(bias + f);
  float4 o;
  o.x = acc.x * inv + bv.x;
  o.y = acc.y * inv + bv.y;
  o.z = acc.z * inv + bv.z;
  o.w = acc.w * inv + bv.w;
  o.x = o.x > 0.f ? o.x : expm1f(o.x);
  o.y = o.y > 0.f ? o.y : expm1f(o.y);
  o.z = o.z > 0.f ? o.z : expm1f(o.z);
  o.w = o.w > 0.f ? o.w : expm1f(o.w);
  *reinterpret_cast<float4*>(out + (size_t)i * FDIM + f) = o;
}

// ---------------- BatchNorm (training-mode batch stats) ----------------
__global__ __launch_bounds__(256) void bn_stats_kernel(
    const float* __restrict__ x, float* __restrict__ sum,
    float* __restrict__ sumsq, int Nn) {
  int fidx = threadIdx.x;
  float s = 0.f, ss = 0.f;
  for (int r = blockIdx.x; r < Nn; r += gridDim.x) {
    float v = x[(size_t)r * FDIM + fidx];
    s += v;
    ss += v * v;
  }
  atomicAdd(&sum[fidx], s);
  atomicAdd(&sumsq[fidx], ss);
}

__device__ inline float bn_elu_one(float v, float s, float q, float g, float b, float invN) {
  float mu = s * invN;
  float var = q * invN - mu * mu;
  var = var > 0.f ? var : 0.f;
  float y = g * (v - mu) * rsqrtf(var + EPSV) + b;
  return y > 0.f ? y : expm1f(y);
}

__global__ __launch_bounds__(256) void bn_apply_elu_kernel(
    const float* __restrict__ x, const float* __restrict__ sum,
    const float* __restrict__ sumsq, const float* __restrict__ gamma,
    const float* __restrict__ beta, float* __restrict__ out, int Nn) {
  size_t idx = (size_t)blockIdx.x * 256 + threadIdx.x;   // one float4 each
  size_t total = (size_t)Nn * (FDIM / 4);
  if (idx >= total) return;
  int f = (int)(idx & (FDIM / 4 - 1)) * 4;
  float invN = 1.f / (float)Nn;
  const float4 v = *reinterpret_cast<const float4*>(x + idx * 4);
  const float4 sv = *reinterpret_cast<const float4*>(sum + f);
  const float4 qv = *reinterpret_cast<const float4*>(sumsq + f);
  const float4 gv = *reinterpret_cast<const float4*>(gamma + f);
  const float4 bv = *reinterpret_cast<const float4*>(beta + f);
  float4 o;
  o.x = bn_elu_one(v.x, sv.x, qv.x, gv.x, bv.x, invN);
  o.y = bn_elu_one(v.y, sv.y, qv.y, gv.y, bv.y, invN);
  o.z = bn_elu_one(v.z, sv.z, qv.z, gv.z, bv.z, invN);
  o.w = bn_elu_one(v.w, sv.w, qv.w, gv.w, bv.w, invN);
  *reinterpret_cast<float4*>(out + idx * 4) = o;
}

// ---------------- launch ----------------
extern "C" void kernel_launch(void* const* d_in, const int* in_sizes, int n_in,
                              void* d_out, int out_size, void* d_ws, size_t ws_size,
                              hipStream_t stream) {
  const float* x   = (const float*)d_in[0];
  const int* edges = (const int*)d_in[1];
  const float* W1  = (const float*)d_in[2];
  const float* a1s = (const float*)d_in[3];
  const float* a1d = (const float*)d_in[4];
  const float* b1  = (const float*)d_in[5];
  const float* W2  = (const float*)d_in[6];
  const float* a2s = (const float*)d_in[7];
  const float* a2d = (const float*)d_in[8];
  const float* b2  = (const float*)d_in[9];
  const float* lw1 = (const float*)d_in[10];
  const float* lb1 = (const float*)d_in[11];
  const float* g1  = (const float*)d_in[12];
  const float* be1 = (const float*)d_in[13];
  const float* lw2 = (const float*)d_in[14];
  const float* lb2 = (const float*)d_in[15];
  const float* g2  = (const float*)d_in[16];
  const float* be2 = (const float*)d_in[17];

  const int F = FDIM;
  int D = in_sizes[2] / F;        // 2613
  int Nn = in_sizes[0] / D;       // 50000
  int E = in_sizes[1] / 2;        // 800000
  const int* srcv = edges;
  const int* dstv = edges + E;
  float* out = (float*)d_out;     // also used as ping buffer (fully overwritten)

  // workspace carve (256B aligned)
  char* p = (char*)d_ws;
  auto alloc = [&](size_t bytes) {
    void* r = (void*)p;
    p += (bytes + 255) & ~(size_t)255;
    return r;
  };
  float* bufA   = (float*)alloc((size_t)Nn * F * 4);
  int* counts   = (int*)alloc((size_t)Nn * 4);
  int* rowst    = (int*)alloc((size_t)(Nn + 1) * 4);
  int* cursor   = (int*)alloc((size_t)Nn * 4);
  int* col_src  = (int*)alloc((size_t)E * 4);
  float* ss     = (float*)alloc((size_t)Nn * 4);
  float* sd     = (float*)alloc((size_t)Nn * 4);
  float* bsum   = (float*)alloc((size_t)F * 4);
  float* bsq    = (float*)alloc((size_t)F * 4);

  // ---- CSR build (reused by both GAT layers) ----
  hipMemsetAsync(counts, 0, (size_t)Nn * 4, stream);
  hipMemsetAsync(cursor, 0, (size_t)Nn * 4, stream);
  count_kernel<<<(E + 255) / 256, 256, 0, stream>>>(dstv, counts, E);
  scan_kernel<<<1, 1024, 0, stream>>>(counts, rowst, Nn);
  fill_kernel<<<(E + 255) / 256, 256, 0, stream>>>(srcv, dstv, rowst, cursor, col_src, E);

  auto launch_gemm = [&](const float* A, const float* B, const float* bias, float* C, int M, int K) {
    dim3 grid((M + 127) / 128, F / 128);
    gemm_f32_kernel<<<grid, 256, 0, stream>>>(A, B, bias, C, M, F, K);
  };

  // ---- GAT layer 1 ----
  launch_gemm(x, W1, nullptr, bufA, Nn, D);                                  // h1 = x @ W1
  scores_kernel<<<Nn, 64, 0, stream>>>(bufA, a1s, a1d, ss, sd);
  gat_aggregate_kernel<<<Nn, 64, 0, stream>>>(bufA, ss, sd, b1, rowst, col_src, out);  // +elu

  // ---- GAT layer 2 ----
  launch_gemm(out, W2, nullptr, bufA, Nn, F);                                // h2 = h @ W2
  scores_kernel<<<Nn, 64, 0, stream>>>(bufA, a2s, a2d, ss, sd);
  gat_aggregate_kernel<<<Nn, 64, 0, stream>>>(bufA, ss, sd, b2, rowst, col_src, out);  // +elu

  // ---- Linear 1 + BN + ELU ----
  launch_gemm(out, lw1, lb1, bufA, Nn, F);                                   // z1
  hipMemsetAsync(bsum, 0, (size_t)F * 4, stream);
  hipMemsetAsync(bsq, 0, (size_t)F * 4, stream);
  bn_stats_kernel<<<512, 256, 0, stream>>>(bufA, bsum, bsq, Nn);
  bn_apply_elu_kernel<<<(Nn * (F / 4) + 255) / 256, 256, 0, stream>>>(bufA, bsum, bsq, g1, be1, out, Nn);

  // ---- Linear 2 + BN + ELU ----
  launch_gemm(out, lw2, lb2, bufA, Nn, F);                                   // z2
  hipMemsetAsync(bsum, 0, (size_t)F * 4, stream);
  hipMemsetAsync(bsq, 0, (size_t)F * 4, stream);
  bn_stats_kernel<<<512, 256, 0, stream>>>(bufA, bsum, bsq, Nn);
  bn_apply_elu_kernel<<<(Nn * (F / 4) + 255) / 256, 256, 0, stream>>>(bufA, bsum, bsq, g2, be2, out, Nn);
}

// Round 2
// 1405.952 us; speedup vs baseline: 1.7441x; 1.7441x over previous
//
#include <hip/hip_runtime.h>
#include <cmath>

#define EPSV 1e-5f
#define NEG_SLOPE 0.2f
#define FDIM 256

typedef __bf16 bf16x8 __attribute__((ext_vector_type(8)));
typedef float f32x4 __attribute__((ext_vector_type(4)));

__device__ __forceinline__ unsigned short f2bf(float x) {
  unsigned int u = __float_as_uint(x);
  unsigned int r = (u + 0x7FFFu + ((u >> 16) & 1u)) >> 16;
  return (unsigned short)r;
}
__device__ __forceinline__ float bf2f(unsigned short b) {
  return __uint_as_float(((unsigned int)b) << 16);
}

__device__ __forceinline__ void async16(const void* g, void* s) {
  __builtin_amdgcn_global_load_lds(
      (const __attribute__((address_space(1))) void*)g,
      (__attribute__((address_space(3))) void*)s, 16, 0, 0);
}

// ---------------- CSR build ----------------
__global__ __launch_bounds__(256) void count_kernel(const int* __restrict__ dstv,
                                                    int* __restrict__ counts, int E) {
  int e = blockIdx.x * 256 + threadIdx.x;
  if (e < E) atomicAdd(&counts[dstv[e]], 1);
}

__global__ __launch_bounds__(1024) void scan_kernel(const int* __restrict__ counts,
                                                    int* __restrict__ row_start, int Nn) {
  __shared__ int lds[1024];
  int t = threadIdx.x;
  int C = (Nn + 1023) >> 10;
  int beg = t * C;
  int end = min(beg + C, Nn);
  int s = 0;
  for (int i = beg; i < end; ++i) s += counts[i];
  lds[t] = s;
  __syncthreads();
  for (int off = 1; off < 1024; off <<= 1) {
    int v = (t >= off) ? lds[t - off] : 0;
    __syncthreads();
    lds[t] += v;
    __syncthreads();
  }
  int run = (t > 0) ? lds[t - 1] : 0;
  for (int i = beg; i < end; ++i) { row_start[i] = run; run += counts[i]; }
  if (t == 1023) row_start[Nn] = lds[1023];
}

__global__ __launch_bounds__(256) void fill_kernel(const int* __restrict__ srcv,
                                                   const int* __restrict__ dstv,
                                                   const int* __restrict__ row_start,
                                                   int* __restrict__ cursor,
                                                   int* __restrict__ col_src, int E) {
  int e = blockIdx.x * 256 + threadIdx.x;
  if (e < E) {
    int d = dstv[e];
    int pos = atomicAdd(&cursor[d], 1);
    col_src[row_start[d] + pos] = srcv[e];
  }
}

// ---------------- weight transpose+convert: W[K][N] fp32 -> Wt[N][Kp] bf16 (zero-padded) ----------------
__global__ __launch_bounds__(256) void transpose_w_kernel(const float* __restrict__ W,
                                                          unsigned short* __restrict__ Wt,
                                                          int K, int N, int Kp) {
  int idx = blockIdx.x * 256 + threadIdx.x;
  if (idx >= N * Kp) return;
  int n = idx / Kp;
  int k = idx - n * Kp;
  Wt[idx] = (k < K) ? f2bf(W[(size_t)k * N + n]) : (unsigned short)0;
}

// ---------------- MFMA bf16 GEMM: C[M][256] = A[M][K] * Bt[256][Kp]^T (+bias), out bf16 ----------------
// BM=BN=128, BK=32, 256 threads (4 waves), each wave 64x64 via 4x4 mfma_16x16x32.
template <bool A_F32>
__global__ __launch_bounds__(256) void gemm_mfma_kernel(
    const void* __restrict__ Av, const unsigned short* __restrict__ Bt,
    const float* __restrict__ bias, unsigned short* __restrict__ C,
    int M, int K, int Kp) {
  const int BM = 128, BN = 128, BK = 32;
  __shared__ __align__(16) unsigned short As[BM * BK];
  __shared__ __align__(16) unsigned short Bs[BN * BK];
  int tid = threadIdx.x;
  int wave = tid >> 6, lane = tid & 63;
  int col0 = blockIdx.x * BN;   // N fastest: two col-blocks of same row panel adjacent in dispatch
  int row0 = blockIdx.y * BM;
  int wr0 = (wave >> 1) * 64, wc0 = (wave & 1) * 64;
  int lrow = lane & 15, kgrp = lane >> 4;

  f32x4 acc[4][4];
#pragma unroll
  for (int i = 0; i < 4; ++i)
#pragma unroll
    for (int j = 0; j < 4; ++j) acc[i][j] = (f32x4){0.f, 0.f, 0.f, 0.f};

  int ktiles = (K + BK - 1) / BK;
  for (int kt = 0; kt < ktiles; ++kt) {
    __syncthreads();
    // ---- stage B tile (async, 2 insts/wave) ----
#pragma unroll
    for (int inst = 0; inst < 2; ++inst) {
      int o = wave * 2048 + inst * 1024 + lane * 16;  // byte offset in Bs
      int row = o >> 6;                               // 64 B per 32-elem row
      int kk = (o & 63) >> 1;
      const unsigned short* g = Bt + (size_t)(col0 + row) * Kp + kt * BK + kk;
      async16(g, (char*)Bs + o);
    }
    // ---- stage A tile ----
    if (A_F32) {
      const float* A = (const float*)Av;
      int r = tid >> 1, kh = (tid & 1) << 4;
      int gr = min(row0 + r, M - 1);
      const float* src = A + (size_t)gr * K + kt * BK + kh;
      int kbase = kt * BK + kh;
      unsigned short tmp[16];
      if (kbase + 16 <= K) {
#pragma unroll
        for (int u = 0; u < 16; ++u) tmp[u] = f2bf(src[u]);
      } else {
#pragma unroll
        for (int u = 0; u < 16; ++u) tmp[u] = (kbase + u < K) ? f2bf(src[u]) : (unsigned short)0;
      }
#pragma unroll
      for (int half = 0; half < 2; ++half) {
        union { unsigned short us[8]; bf16x8 v; } w;
#pragma unroll
        for (int u = 0; u < 8; ++u) w.us[u] = tmp[half * 8 + u];
        *(bf16x8*)&As[r * BK + kh + half * 8] = w.v;
      }
    } else {
      const unsigned short* A = (const unsigned short*)Av;
#pragma unroll
      for (int inst = 0; inst < 2; ++inst) {
        int o = wave * 2048 + inst * 1024 + lane * 16;
        int row = o >> 6;
        int kk = (o & 63) >> 1;
        int gr = min(row0 + row, M - 1);
        const unsigned short* g = A + (size_t)gr * Kp + kt * BK + kk;
        async16(g, (char*)As + o);
      }
    }
    __syncthreads();
    // ---- compute ----
    bf16x8 aF[4], bF[4];
#pragma unroll
    for (int i = 0; i < 4; ++i)
      aF[i] = *(const bf16x8*)&As[(wr0 + i * 16 + lrow) * BK + kgrp * 8];
#pragma unroll
    for (int j = 0; j < 4; ++j)
      bF[j] = *(const bf16x8*)&Bs[(wc0 + j * 16 + lrow) * BK + kgrp * 8];
#pragma unroll
    for (int i = 0; i < 4; ++i)
#pragma unroll
      for (int j = 0; j < 4; ++j)
        acc[i][j] = __builtin_amdgcn_mfma_f32_16x16x32_bf16(aF[i], bF[j], acc[i][j], 0, 0, 0);
  }
  // ---- epilogue ----
  float bcol[4] = {0.f, 0.f, 0.f, 0.f};
  if (bias) {
#pragma unroll
    for (int j = 0; j < 4; ++j) bcol[j] = bias[col0 + wc0 + j * 16 + lrow];
  }
#pragma unroll
  for (int i = 0; i < 4; ++i) {
#pragma unroll
    for (int r = 0; r < 4; ++r) {
      int row = row0 + wr0 + i * 16 + kgrp * 4 + r;
      if (row < M) {
        unsigned short* Crow = C + (size_t)row * FDIM;
#pragma unroll
        for (int j = 0; j < 4; ++j)
          Crow[col0 + wc0 + j * 16 + lrow] = f2bf(acc[i][j][r] + bcol[j]);
      }
    }
  }
}

// ---------------- attention scores from bf16 h ----------------
__global__ __launch_bounds__(64) void scores_kernel(
    const unsigned short* __restrict__ h, const float* __restrict__ a_src,
    const float* __restrict__ a_dst, float* __restrict__ s_src,
    float* __restrict__ s_dst) {
  int node = blockIdx.x;
  int lane = threadIdx.x;
  ushort4 hv = *reinterpret_cast<const ushort4*>(h + (size_t)node * FDIM + lane * 4);
  const float4 as = *reinterpret_cast<const float4*>(a_src + lane * 4);
  const float4 ad = *reinterpret_cast<const float4*>(a_dst + lane * 4);
  float h0 = bf2f(hv.x), h1 = bf2f(hv.y), h2 = bf2f(hv.z), h3 = bf2f(hv.w);
  float vs = h0 * as.x + h1 * as.y + h2 * as.z + h3 * as.w;
  float vd = h0 * ad.x + h1 * ad.y + h2 * ad.z + h3 * ad.w;
#pragma unroll
  for (int off = 32; off > 0; off >>= 1) {
    vs += __shfl_down(vs, off);
    vd += __shfl_down(vd, off);
  }
  if (lane == 0) { s_src[node] = vs; s_dst[node] = vd; }
}

// ---------------- GAT aggregate (online softmax) + bias + ELU, bf16 in/out ----------------
__global__ __launch_bounds__(64) void gat_aggregate_kernel(
    const unsigned short* __restrict__ h, const float* __restrict__ s_src,
    const float* __restrict__ s_dst, const float* __restrict__ bias,
    const int* __restrict__ row_start, const int* __restrict__ col_src,
    unsigned short* __restrict__ out) {
  int i = blockIdx.x;
  int lane = threadIdx.x;
  int f = lane * 4;
  float sd = s_dst[i];
  float e0 = s_src[i] + sd;
  e0 = e0 > 0.f ? e0 : NEG_SLOPE * e0;
  float m = e0, l = 1.f;
  ushort4 hv = *reinterpret_cast<const ushort4*>(h + (size_t)i * FDIM + f);
  float4 acc = make_float4(bf2f(hv.x), bf2f(hv.y), bf2f(hv.z), bf2f(hv.w));
  int beg = row_start[i], end = row_start[i + 1];
  for (int p = beg; p < end; ++p) {
    int j = col_src[p];
    float e = s_src[j] + sd;
    e = e > 0.f ? e : NEG_SLOPE * e;
    float mn = fmaxf(m, e);
    float sc = __expf(m - mn);
    float pw = __expf(e - mn);
    l = l * sc + pw;
    ushort4 hj = *reinterpret_cast<const ushort4*>(h + (size_t)j * FDIM + f);
    acc.x = acc.x * sc + pw * bf2f(hj.x);
    acc.y = acc.y * sc + pw * bf2f(hj.y);
    acc.z = acc.z * sc + pw * bf2f(hj.z);
    acc.w = acc.w * sc + pw * bf2f(hj.w);
    m = mn;
  }
  float inv = 1.f / l;
  const float4 bv = *reinterpret_cast<const float4*>(bias + f);
  float4 o;
  o.x = acc.x * inv + bv.x;
  o.y = acc.y * inv + bv.y;
  o.z = acc.z * inv + bv.z;
  o.w = acc.w * inv + bv.w;
  o.x = o.x > 0.f ? o.x : expm1f(o.x);
  o.y = o.y > 0.f ? o.y : expm1f(o.y);
  o.z = o.z > 0.f ? o.z : expm1f(o.z);
  o.w = o.w > 0.f ? o.w : expm1f(o.w);
  ushort4 ov = make_ushort4(f2bf(o.x), f2bf(o.y), f2bf(o.z), f2bf(o.w));
  *reinterpret_cast<ushort4*>(out + (size_t)i * FDIM + f) = ov;
}

// ---------------- BatchNorm ----------------
__global__ __launch_bounds__(256) void bn_stats_kernel(
    const unsigned short* __restrict__ x, float* __restrict__ sum,
    float* __restrict__ sumsq, int Nn) {
  int fidx = threadIdx.x;
  float s = 0.f, ss = 0.f;
  for (int r = blockIdx.x; r < Nn; r += gridDim.x) {
    float v = bf2f(x[(size_t)r * FDIM + fidx]);
    s += v;
    ss += v * v;
  }
  atomicAdd(&sum[fidx], s);
  atomicAdd(&sumsq[fidx], ss);
}

__device__ __forceinline__ float bn_elu_one(float v, float s, float q, float g, float b, float invN) {
  float mu = s * invN;
  float var = q * invN - mu * mu;
  var = var > 0.f ? var : 0.f;
  float y = g * (v - mu) * rsqrtf(var + EPSV) + b;
  return y > 0.f ? y : expm1f(y);
}

template <bool OUTF32>
__global__ __launch_bounds__(256) void bn_apply_elu_kernel(
    const unsigned short* __restrict__ x, const float* __restrict__ sum,
    const float* __restrict__ sumsq, const float* __restrict__ gamma,
    const float* __restrict__ beta, void* __restrict__ outv, int Nn) {
  size_t idx = (size_t)blockIdx.x * 256 + threadIdx.x;  // 4 features each
  size_t total = (size_t)Nn * (FDIM / 4);
  if (idx >= total) return;
  int f = (int)(idx & (FDIM / 4 - 1)) * 4;
  float invN = 1.f / (float)Nn;
  ushort4 v = *reinterpret_cast<const ushort4*>(x + idx * 4);
  const float4 sv = *reinterpret_cast<const float4*>(sum + f);
  const float4 qv = *reinterpret_cast<const float4*>(sumsq + f);
  const float4 gv = *reinterpret_cast<const float4*>(gamma + f);
  const float4 bv = *reinterpret_cast<const float4*>(beta + f);
  float4 o;
  o.x = bn_elu_one(bf2f(v.x), sv.x, qv.x, gv.x, bv.x, invN);
  o.y = bn_elu_one(bf2f(v.y), sv.y, qv.y, gv.y, bv.y, invN);
  o.z = bn_elu_one(bf2f(v.z), sv.z, qv.z, gv.z, bv.z, invN);
  o.w = bn_elu_one(bf2f(v.w), sv.w, qv.w, gv.w, bv.w, invN);
  if (OUTF32) {
    reinterpret_cast<float4*>(outv)[idx] = o;
  } else {
    ushort4 ov = make_ushort4(f2bf(o.x), f2bf(o.y), f2bf(o.z), f2bf(o.w));
    reinterpret_cast<ushort4*>(outv)[idx] = ov;
  }
}

// ---------------- launch ----------------
extern "C" void kernel_launch(void* const* d_in, const int* in_sizes, int n_in,
                              void* d_out, int out_size, void* d_ws, size_t ws_size,
                              hipStream_t stream) {
  const float* x   = (const float*)d_in[0];
  const int* edges = (const int*)d_in[1];
  const float* W1  = (const float*)d_in[2];
  const float* a1s = (const float*)d_in[3];
  const float* a1d = (const float*)d_in[4];
  const float* b1  = (const float*)d_in[5];
  const float* W2  = (const float*)d_in[6];
  const float* a2s = (const float*)d_in[7];
  const float* a2d = (const float*)d_in[8];
  const float* b2  = (const float*)d_in[9];
  const float* lw1 = (const float*)d_in[10];
  const float* lb1 = (const float*)d_in[11];
  const float* g1  = (const float*)d_in[12];
  const float* be1 = (const float*)d_in[13];
  const float* lw2 = (const float*)d_in[14];
  const float* lb2 = (const float*)d_in[15];
  const float* g2  = (const float*)d_in[16];
  const float* be2 = (const float*)d_in[17];

  const int F = FDIM;
  int D = in_sizes[2] / F;        // 2613
  int Nn = in_sizes[0] / D;       // 50000
  int E = in_sizes[1] / 2;        // 800000
  int Kp1 = ((D + 31) / 32) * 32; // 2624
  const int* srcv = edges;
  const int* dstv = edges + E;

  char* p = (char*)d_ws;
  auto alloc = [&](size_t bytes) {
    void* r = (void*)p;
    p += (bytes + 255) & ~(size_t)255;
    return r;
  };
  unsigned short* W1t  = (unsigned short*)alloc((size_t)F * Kp1 * 2);
  unsigned short* W2t  = (unsigned short*)alloc((size_t)F * F * 2);
  unsigned short* lw1t = (unsigned short*)alloc((size_t)F * F * 2);
  unsigned short* lw2t = (unsigned short*)alloc((size_t)F * F * 2);
  unsigned short* bufH = (unsigned short*)alloc((size_t)Nn * F * 2);
  unsigned short* bufG = (unsigned short*)alloc((size_t)Nn * F * 2);
  int* counts  = (int*)alloc((size_t)Nn * 4);
  int* rowst   = (int*)alloc((size_t)(Nn + 1) * 4);
  int* cursor  = (int*)alloc((size_t)Nn * 4);
  int* col_src = (int*)alloc((size_t)E * 4);
  float* ss    = (float*)alloc((size_t)Nn * 4);
  float* sd    = (float*)alloc((size_t)Nn * 4);
  float* bsum  = (float*)alloc((size_t)F * 4);
  float* bsq   = (float*)alloc((size_t)F * 4);

  // ---- CSR build ----
  hipMemsetAsync(counts, 0, (size_t)Nn * 4, stream);
  hipMemsetAsync(cursor, 0, (size_t)Nn * 4, stream);
  count_kernel<<<(E + 255) / 256, 256, 0, stream>>>(dstv, counts, E);
  scan_kernel<<<1, 1024, 0, stream>>>(counts, rowst, Nn);
  fill_kernel<<<(E + 255) / 256, 256, 0, stream>>>(srcv, dstv, rowst, cursor, col_src, E);

  // ---- weight convert/transpose ----
  transpose_w_kernel<<<(F * Kp1 + 255) / 256, 256, 0, stream>>>(W1, W1t, D, F, Kp1);
  transpose_w_kernel<<<(F * F + 255) / 256, 256, 0, stream>>>(W2, W2t, F, F, F);
  transpose_w_kernel<<<(F * F + 255) / 256, 256, 0, stream>>>(lw1, lw1t, F, F, F);
  transpose_w_kernel<<<(F * F + 255) / 256, 256, 0, stream>>>(lw2, lw2t, F, F, F);

  dim3 ggrid(F / 128, (Nn + 127) / 128);

  // ---- GAT layer 1 ----
  gemm_mfma_kernel<true><<<ggrid, 256, 0, stream>>>(x, W1t, nullptr, bufH, Nn, D, Kp1);
  scores_kernel<<<Nn, 64, 0, stream>>>(bufH, a1s, a1d, ss, sd);
  gat_aggregate_kernel<<<Nn, 64, 0, stream>>>(bufH, ss, sd, b1, rowst, col_src, bufG);

  // ---- GAT layer 2 ----
  gemm_mfma_kernel<false><<<ggrid, 256, 0, stream>>>(bufG, W2t, nullptr, bufH, Nn, F, F);
  scores_kernel<<<Nn, 64, 0, stream>>>(bufH, a2s, a2d, ss, sd);
  gat_aggregate_kernel<<<Nn, 64, 0, stream>>>(bufH, ss, sd, b2, rowst, col_src, bufG);

  // ---- Linear 1 + BN + ELU ----
  gemm_mfma_kernel<false><<<ggrid, 256, 0, stream>>>(bufG, lw1t, lb1, bufH, Nn, F, F);
  hipMemsetAsync(bsum, 0, (size_t)F * 4, stream);
  hipMemsetAsync(bsq, 0, (size_t)F * 4, stream);
  bn_stats_kernel<<<512, 256, 0, stream>>>(bufH, bsum, bsq, Nn);
  bn_apply_elu_kernel<false><<<(Nn * (F / 4) + 255) / 256, 256, 0, stream>>>(
      bufH, bsum, bsq, g1, be1, bufG, Nn);

  // ---- Linear 2 + BN + ELU (final out fp32) ----
  gemm_mfma_kernel<false><<<ggrid, 256, 0, stream>>>(bufG, lw2t, lb2, bufH, Nn, F, F);
  hipMemsetAsync(bsum, 0, (size_t)F * 4, stream);
  hipMemsetAsync(bsq, 0, (size_t)F * 4, stream);
  bn_stats_kernel<<<512, 256, 0, stream>>>(bufH, bsum, bsq, Nn);
  bn_apply_elu_kernel<true><<<(Nn * (F / 4) + 255) / 256, 256, 0, stream>>>(
      bufH, bsum, bsq, g2, be2, d_out, Nn);
}